// Round 14
// baseline (389.690 us; speedup 1.0000x reference)
//
#include <hip/hip_runtime.h>
#include <cstdint>

typedef __bf16 bf16;
typedef __attribute__((ext_vector_type(8))) __bf16 bf16x8;
typedef __attribute__((ext_vector_type(4))) float f32x4;

#define CEPS 1e-5f
#define MROWS 65536   // B*T
#define NB 2048       // B
#define CDIM 512
#define K3C 1536
#define MKT 24        // K3C / 64

// fast gelu: tanh form via native exp; |err| <= ~3e-3 absolute
__device__ __forceinline__ float gelu_f(float x) {
  float x2 = x * x;
  float u = x * (0.7978845608f + 0.0356774081f * x2);
  float e = __expf(2.0f * u);
  float th = 1.0f - __fdividef(2.0f, e + 1.0f);
  return 0.5f * x * (1.0f + th);
}

__device__ __forceinline__ void gload_lds16(const void* g, void* l) {
  using GP = const __attribute__((address_space(1))) void*;
  using LP = __attribute__((address_space(3))) void*;
  __builtin_amdgcn_global_load_lds(reinterpret_cast<GP>(reinterpret_cast<uintptr_t>(g)),
                                   reinterpret_cast<LP>(reinterpret_cast<uintptr_t>(l)),
                                   16, 0, 0);
}

__device__ __forceinline__ int xcd_swz(int bid, int nwg) {
  int q = nwg >> 3, r = nwg & 7;
  int xcd = bid & 7, i = bid >> 3;
  return (xcd < r ? xcd * (q + 1) : r * (q + 1) + (xcd - r) * q) + i;
}

// ---------------- fold kernel
__global__ __launch_bounds__(256) void fold_kernel(
    const float* __restrict__ wmix, const float* __restrict__ bnm_g, const float* __restrict__ bnm_v,
    const float* __restrict__ edg, const float* __restrict__ edb,
    const float* __restrict__ esg, const float* __restrict__ esb,
    const float* __restrict__ w1a, const float* __restrict__ w1b,
    const float* __restrict__ b1a, const float* __restrict__ b1b,
    bf16* __restrict__ wmixf, bf16* __restrict__ w1f, float* __restrict__ b1f) {
  __shared__ float red[4];
  int bid = blockIdx.x, tid = threadIdx.x;
  if (bid < 512) {
    int o = bid;
    float s = bnm_g[o] * rsqrtf(bnm_v[o] + CEPS);
    for (int c = tid; c < K3C; c += 256)
      wmixf[(size_t)o * K3C + c] = (bf16)(wmix[(size_t)o * K3C + c] * s);
  } else {
    int n = bid - 512;
    int half = (n < 256) ? 0 : 1;
    const float* g  = half ? esg : edg;
    const float* lb = half ? esb : edb;
    const float* w1 = half ? w1b : w1a;
    const float* b1 = half ? b1b : b1a;
    int nn = n & 255;
    float dot = 0.f;
    for (int c = tid; c < 512; c += 256) {
      float w = w1[(size_t)nn * 512 + c];
      w1f[(size_t)n * 512 + c] = (bf16)(w * g[c]);
      dot += w * lb[c];
    }
    #pragma unroll
    for (int off = 1; off < 64; off <<= 1) dot += __shfl_xor(dot, off, 64);
    if ((tid & 63) == 0) red[tid >> 6] = dot;
    __syncthreads();
    if (tid == 0) b1f[n] = b1[nn] + red[0] + red[1] + red[2] + red[3];
  }
}

// ---------------- prep (v1, proven)
__global__ __launch_bounds__(512) void prep_kernel(
    const float* __restrict__ x,
    const float* __restrict__ w3, const float* __restrict__ bn3g, const float* __restrict__ bn3b,
    const float* __restrict__ bn3m, const float* __restrict__ bn3v,
    const float* __restrict__ w5, const float* __restrict__ bn5g, const float* __restrict__ bn5b,
    const float* __restrict__ bn5m, const float* __restrict__ bn5v,
    bf16* __restrict__ Acat) {
  int b = blockIdx.x, c = threadIdx.x;
  const float4* xp = (const float4*)(x + ((size_t)b * 512 + c) * 64);
  float tf[32];
  #pragma unroll
  for (int i = 0; i < 16; i++) {
    float4 v = xp[i];
    tf[2 * i]     = 0.5f * (v.x + v.y);
    tf[2 * i + 1] = 0.5f * (v.z + v.w);
  }
  float s3 = bn3g[c] * rsqrtf(bn3v[c] + CEPS), t3 = bn3b[c] - bn3m[c] * s3;
  float s5 = bn5g[c] * rsqrtf(bn5v[c] + CEPS), t5 = bn5b[c] - bn5m[c] * s5;
  float w30 = w3[c * 3], w31 = w3[c * 3 + 1], w32 = w3[c * 3 + 2];
  float w50 = w5[c * 5], w51 = w5[c * 5 + 1], w52 = w5[c * 5 + 2], w53 = w5[c * 5 + 3], w54 = w5[c * 5 + 4];
  bf16* Ab = Acat + (size_t)b * 32 * K3C + c;
  #pragma unroll
  for (int t = 0; t < 32; t++) {
    float tm2 = (t >= 2) ? tf[t - 2] : 0.f;
    float tm1 = (t >= 1) ? tf[t - 1] : 0.f;
    float tp1 = (t < 31) ? tf[t + 1] : 0.f;
    float tp2 = (t < 30) ? tf[t + 2] : 0.f;
    float c3 = gelu_f((w30 * tm1 + w31 * tf[t] + w32 * tp1) * s3 + t3);
    float c5 = gelu_f((w50 * tm2 + w51 * tm1 + w52 * tf[t] + w53 * tp1 + w54 * tp2) * s5 + t5);
    Ab[t * K3C]        = (bf16)tf[t];
    Ab[t * K3C + 512]  = (bf16)c3;
    Ab[t * K3C + 1024] = (bf16)c5;
  }
}

// ---------------- mega kernel
#define MFMA1 __builtin_amdgcn_mfma_f32_16x16x32_bf16

#define PHASE(q)                                                              \
  {                                                                           \
    bf16x8 Bf[2][2];                                                          \
    _Pragma("unroll")                                                         \
    for (int i = 0; i < 2; i++) {                                             \
      Bf[i][0] = *(const bf16x8*)(lds + sl + bOff0 + (q) * 16384 + i * 2048); \
      Bf[i][1] = *(const bf16x8*)(lds + sl + bOff1 + (q) * 16384 + i * 2048); \
    }                                                                         \
    __builtin_amdgcn_s_barrier();                                             \
    __builtin_amdgcn_s_setprio(1);                                            \
    _Pragma("unroll")                                                         \
    for (int k2 = 0; k2 < 2; k2++)                                            \
      _Pragma("unroll")                                                       \
      for (int i = 0; i < 2; i++)                                             \
        _Pragma("unroll")                                                     \
        for (int mr = 0; mr < 4; mr++)                                        \
          acc[mr][2 * (q) + i] = MFMA1(Af[mr][k2], Bf[i][k2], acc[mr][2 * (q) + i], 0, 0, 0); \
    __builtin_amdgcn_s_setprio(0);                                            \
    if (stB) stageBq(sl, (q), t + 2);                                         \
  }

__global__ __launch_bounds__(512, 1) void mega_kernel(
    const bf16* __restrict__ Acat, const bf16* __restrict__ Bw, const bf16* __restrict__ w1f,
    const float* __restrict__ bn_g, const float* __restrict__ bn_b,
    const float* __restrict__ bn_m, const float* __restrict__ bn_v,
    const float* __restrict__ pos, const float* __restrict__ lng, const float* __restrict__ lnb,
    const float* __restrict__ b1f, const float* __restrict__ w2a, const float* __restrict__ w2b,
    const float* __restrict__ ta, const float* __restrict__ tb,
    float* __restrict__ feats, float* __restrict__ pair, float* __restrict__ pooled) {
  __shared__ char lds[163840];
  int tid = threadIdx.x;
  int wv = tid >> 6, lane = tid & 63;
  int wm = wv >> 2, wn = wv & 3;
  int fr = lane & 15, kq = lane >> 4;
  int mb = xcd_swz(blockIdx.x, gridDim.x);   // 512 m-blocks

  const size_t AKB = 3072;
  const char* Ablk = (const char*)Acat + (size_t)mb * 128 * AKB;

  int r8 = tid >> 3;
  int colx = ((tid & 7) << 4) ^ ((r8 & 7) << 4);
  const char* pA = Ablk + (size_t)r8 * AKB + colx;
  int r32 = r8 & 31, st0 = r8 >> 5;
  const char* pB = (const char*)Bw + (size_t)(st0 * 128 + r32) * AKB
                 + (((tid & 7) << 4) ^ ((r32 & 7) << 4));
  const int dstIdx = tid * 16;

  int e0 = (kq << 4) ^ ((fr & 7) << 4);
  int e1 = (64 | (kq << 4)) ^ ((fr & 7) << 4);
  int aB_ = (wm * 64 + fr) * 128;
  int bB_ = 16384 + (wn * 32 + fr) * 128;
  const int aOff0 = aB_ + e0, aOff1 = aB_ + e1;
  const int bOff0 = bB_ + e0, bOff1 = bB_ + e1;

  auto stageA = [&](int slot, int t) {
    char* d = lds + slot + dstIdx;
    const char* s = pA + (size_t)t * 128;
    gload_lds16(s, d);
    gload_lds16(s + 64 * AKB, d + 8192);
  };
  auto stageBq = [&](int slot, int q, int t) {
    char* d = lds + slot + 16384 + q * 16384 + dstIdx;
    const char* s = pB + (size_t)q * 32 * AKB + (size_t)t * 128;
    gload_lds16(s, d);
    gload_lds16(s + 256 * AKB, d + 8192);
  };

  const f32x4 fz = {0.f, 0.f, 0.f, 0.f};
  f32x4 acc[4][8];
  #pragma unroll
  for (int i = 0; i < 4; i++)
    #pragma unroll
    for (int j = 0; j < 8; j++) acc[i][j] = fz;

  stageA(0, 0);
  #pragma unroll
  for (int q = 0; q < 4; q++) stageBq(0, q, 0);
  #pragma unroll
  for (int q = 0; q < 4; q++) stageBq(81920, q, 1);
  asm volatile("s_waitcnt vmcnt(8)" ::: "memory");
  __builtin_amdgcn_s_barrier();

  for (int t = 0; t < MKT; t++) {
    const int sl = (t & 1) * 81920;
    const bool stA = (t + 1 < MKT), stB = (t + 2 < MKT);
    if (stA) stageA(sl ^ 81920, t + 1);
    bf16x8 Af[4][2];
    #pragma unroll
    for (int mr = 0; mr < 4; mr++) {
      Af[mr][0] = *(const bf16x8*)(lds + sl + aOff0 + mr * 2048);
      Af[mr][1] = *(const bf16x8*)(lds + sl + aOff1 + mr * 2048);
    }
    PHASE(0);
    __builtin_amdgcn_s_barrier();
    PHASE(1);
    __builtin_amdgcn_s_barrier();
    PHASE(2);
    __builtin_amdgcn_s_barrier();
    PHASE(3);
    if (t < MKT - 2) {
      asm volatile("s_waitcnt vmcnt(8)" ::: "memory");
    } else if (t == MKT - 2) {
      asm volatile("s_waitcnt vmcnt(0)" ::: "memory");
    }
    __builtin_amdgcn_s_barrier();
  }

  // ---- E1: ctx = gelu(acc + bn_bias) in-register
  {
    float biasm[8];
    #pragma unroll
    for (int nr = 0; nr < 8; nr++) {
      int n = wn * 128 + nr * 16 + fr;
      float s = bn_g[n] * rsqrtf(bn_v[n] + CEPS);
      biasm[nr] = bn_b[n] - bn_m[n] * s;
    }
    #pragma unroll
    for (int mr = 0; mr < 4; mr++)
      #pragma unroll
      for (int nr = 0; nr < 8; nr++)
        #pragma unroll
        for (int j = 0; j < 4; j++)
          acc[mr][nr][j] = gelu_f(acc[mr][nr][j] + biasm[nr]);
  }
  __syncthreads();
  // ---- E2: stage tf tile [128 rows][1024B] swizzled into lds[0..131072)
  {
    const char* ptf = Ablk + (size_t)wv * AKB + ((lane * 16) ^ (wv << 4));
    char* d = lds + wv * 1024 + lane * 16;
    #pragma unroll
    for (int l = 0; l < 16; l++) gload_lds16(ptf + (size_t)l * 8 * AKB, d + l * 8192);
  }
  __syncthreads();
  float* sst  = (float*)(lds + 131072);   // [128][4] float2
  float* minv = (float*)(lds + 135168);   // [128] float2 (mu, inv) — survives to E9 now
  // ---- E3: z = ctx + tf + pos; stats1
  {
    float s1[4][4], s2[4][4];
    #pragma unroll
    for (int mr = 0; mr < 4; mr++)
      #pragma unroll
      for (int j = 0; j < 4; j++) { s1[mr][j] = 0.f; s2[mr][j] = 0.f; }
    #pragma unroll
    for (int mr = 0; mr < 4; mr++)
      #pragma unroll
      for (int j = 0; j < 4; j++) {
        int r = wm * 64 + mr * 16 + kq * 4 + j;
        int swz = (r & 7) << 4;
        #pragma unroll
        for (int nr = 0; nr < 8; nr++) {
          int c = wn * 128 + nr * 16 + fr;
          float tfv = (float)*(const bf16*)(lds + r * 1024 + ((c * 2) ^ swz));
          float z = acc[mr][nr][j] + tfv + pos[(r & 31) * 512 + c];
          acc[mr][nr][j] = z;
          s1[mr][j] += z; s2[mr][j] += z * z;
        }
      }
    #pragma unroll
    for (int mr = 0; mr < 4; mr++)
      #pragma unroll
      for (int j = 0; j < 4; j++)
        #pragma unroll
        for (int off = 1; off < 16; off <<= 1) {
          s1[mr][j] += __shfl_xor(s1[mr][j], off, 64);
          s2[mr][j] += __shfl_xor(s2[mr][j], off, 64);
        }
    if (fr == 0) {
      #pragma unroll
      for (int mr = 0; mr < 4; mr++)
        #pragma unroll
        for (int j = 0; j < 4; j++) {
          int r = wm * 64 + mr * 16 + kq * 4 + j;
          ((float2*)sst)[r * 4 + wn] = make_float2(s1[mr][j], s2[mr][j]);
        }
    }
  }
  __syncthreads();
  if (tid < 128) {
    float a = 0.f, b = 0.f;
    #pragma unroll
    for (int w = 0; w < 4; w++) { float2 v = ((float2*)sst)[tid * 4 + w]; a += v.x; b += v.y; }
    float mu = a * (1.f / 512.f);
    float var = b * (1.f / 512.f) - mu * mu;
    ((float2*)minv)[tid] = make_float2(mu, rsqrtf(var + CEPS));
  }
  __syncthreads();
  // ---- E5: feats = (z-mu)*inv*g + b; stats2
  {
    float g_[8], b_[8];
    #pragma unroll
    for (int nr = 0; nr < 8; nr++) {
      int c = wn * 128 + nr * 16 + fr;
      g_[nr] = lng[c]; b_[nr] = lnb[c];
    }
    float t1[4][4], t2[4][4];
    #pragma unroll
    for (int mr = 0; mr < 4; mr++)
      #pragma unroll
      for (int j = 0; j < 4; j++) { t1[mr][j] = 0.f; t2[mr][j] = 0.f; }
    #pragma unroll
    for (int mr = 0; mr < 4; mr++)
      #pragma unroll
      for (int j = 0; j < 4; j++) {
        int r = wm * 64 + mr * 16 + kq * 4 + j;
        float2 mi = ((float2*)minv)[r];
        #pragma unroll
        for (int nr = 0; nr < 8; nr++) {
          int c = wn * 128 + nr * 16 + fr;
          float f = (acc[mr][nr][j] - mi.x) * mi.y * g_[nr] + b_[nr];
          acc[mr][nr][j] = f;
          feats[((size_t)mb * 128 + r) * 512 + c] = f;
          t1[mr][j] += f; t2[mr][j] += f * f;
        }
      }
    #pragma unroll
    for (int mr = 0; mr < 4; mr++)
      #pragma unroll
      for (int j = 0; j < 4; j++)
        #pragma unroll
        for (int off = 1; off < 16; off <<= 1) {
          t1[mr][j] += __shfl_xor(t1[mr][j], off, 64);
          t2[mr][j] += __shfl_xor(t2[mr][j], off, 64);
        }
    __syncthreads();
    if (fr == 0) {
      #pragma unroll
      for (int mr = 0; mr < 4; mr++)
        #pragma unroll
        for (int j = 0; j < 4; j++) {
          int r = wm * 64 + mr * 16 + kq * 4 + j;
          ((float2*)sst)[r * 4 + wn] = make_float2(t1[mr][j], t2[mr][j]);
        }
    }
  }
  __syncthreads();
  if (tid < 128) {
    float a = 0.f, b = 0.f;
    #pragma unroll
    for (int w = 0; w < 4; w++) { float2 v = ((float2*)sst)[tid * 4 + w]; a += v.x; b += v.y; }
    float mu = a * (1.f / 512.f);
    float var = b * (1.f / 512.f) - mu * mu;
    ((float2*)minv)[tid] = make_float2(mu, rsqrtf(var + CEPS));
  }
  __syncthreads();
  // ---- E6: zhat -> LDS [0..131072), swizzled; alive through pooled
  #pragma unroll
  for (int mr = 0; mr < 4; mr++)
    #pragma unroll
    for (int j = 0; j < 4; j++) {
      int r = wm * 64 + mr * 16 + kq * 4 + j;
      int swz = (r & 7) << 4;
      float2 mi = ((float2*)minv)[r];
      #pragma unroll
      for (int nr = 0; nr < 8; nr++) {
        int c = wn * 128 + nr * 16 + fr;
        *(bf16*)(lds + r * 1024 + ((c * 2) ^ swz)) = (bf16)((acc[mr][nr][j] - mi.x) * mi.y);
      }
    }
  __syncthreads();
  // ---- E7: attn h-GEMM; A from zhat LDS, B reg-double-buffered from L2-hot w1f
  //      (no barriers, no LDS staging -> minv region untouched, miKeep removed)
  #pragma unroll
  for (int i = 0; i < 4; i++)
    #pragma unroll
    for (int j = 0; j < 8; j++) acc[i][j] = fz;
  float b1l[8], w2l[8];
  #pragma unroll
  for (int h = 0; h < 2; h++) {
    float tv = fminf(fmaxf(h ? tb[0] : ta[0], 0.25f), 4.0f);
    #pragma unroll
    for (int nr = 0; nr < 4; nr++) {
      int np = wn * 64 + nr * 16 + fr;
      b1l[h * 4 + nr] = b1f[h * 256 + np];
      w2l[h * 4 + nr] = (h ? w2b[np] : w2a[np]) / tv;
    }
  }
  {
    const char* pWb = (const char*)w1f + (size_t)(wn * 64 + fr) * 1024 + (kq << 4);
    int azB = (wm * 64 + fr) * 1024;
    const int azOff0 = azB + e0, azOff1 = azB + e1;
    #pragma unroll
    for (int h = 0; h < 2; h++) {
      const char* pH = pWb + h * 262144;
      bf16x8 Bc[4][2], Bn[4][2];
      #pragma unroll
      for (int nr = 0; nr < 4; nr++) {
        Bc[nr][0] = *(const bf16x8*)(pH + nr * 16384);
        Bc[nr][1] = *(const bf16x8*)(pH + nr * 16384 + 64);
      }
      #pragma unroll
      for (int kk = 0; kk < 8; kk++) {
        if (kk < 7) {
          #pragma unroll
          for (int nr = 0; nr < 4; nr++) {
            Bn[nr][0] = *(const bf16x8*)(pH + nr * 16384 + (kk + 1) * 128);
            Bn[nr][1] = *(const bf16x8*)(pH + nr * 16384 + (kk + 1) * 128 + 64);
          }
        }
        bf16x8 Az[4][2];
        #pragma unroll
        for (int mr = 0; mr < 4; mr++) {
          Az[mr][0] = *(const bf16x8*)(lds + azOff0 + mr * 16384 + kk * 128);
          Az[mr][1] = *(const bf16x8*)(lds + azOff1 + mr * 16384 + kk * 128);
        }
        __builtin_amdgcn_s_setprio(1);
        #pragma unroll
        for (int k2 = 0; k2 < 2; k2++)
          #pragma unroll
          for (int mr = 0; mr < 4; mr++)
            #pragma unroll
            for (int nr = 0; nr < 4; nr++)
              acc[mr][h * 4 + nr] = MFMA1(Az[mr][k2], Bc[nr][k2], acc[mr][h * 4 + nr], 0, 0, 0);
        __builtin_amdgcn_s_setprio(0);
        #pragma unroll
        for (int nr = 0; nr < 4; nr++) { Bc[nr][0] = Bn[nr][0]; Bc[nr][1] = Bn[nr][1]; }
      }
    }
  }
  // ---- E8: path partials: sstE/sstS[r][wn]
  float* sstE = (float*)(lds + 131072);  // [128][4]
  float* sstS = (float*)(lds + 133120);
  {
    float pE[4][4], pS[4][4];
    #pragma unroll
    for (int mr = 0; mr < 4; mr++)
      #pragma unroll
      for (int j = 0; j < 4; j++) { pE[mr][j] = 0.f; pS[mr][j] = 0.f; }
    #pragma unroll
    for (int mr = 0; mr < 4; mr++)
      #pragma unroll
      for (int j = 0; j < 4; j++)
        #pragma unroll
        for (int q8 = 0; q8 < 8; q8++) {
          float hh = gelu_f(acc[mr][q8][j] + b1l[q8]) * w2l[q8];
          if (q8 < 4) pE[mr][j] += hh; else pS[mr][j] += hh;
        }
    #pragma unroll
    for (int mr = 0; mr < 4; mr++)
      #pragma unroll
      for (int j = 0; j < 4; j++)
        #pragma unroll
        for (int off = 1; off < 16; off <<= 1) {
          pE[mr][j] += __shfl_xor(pE[mr][j], off, 64);
          pS[mr][j] += __shfl_xor(pS[mr][j], off, 64);
        }
    if (fr == 0) {
      #pragma unroll
      for (int mr = 0; mr < 4; mr++)
        #pragma unroll
        for (int j = 0; j < 4; j++) {
          int r = wm * 64 + mr * 16 + kq * 4 + j;
          sstE[r * 4 + wn] = pE[mr][j];
          sstS[r * 4 + wn] = pS[mr][j];
        }
    }
  }
  __syncthreads();
  // ---- E9: softmax over T per batch; pair; pooled weights (minv read directly)
  float* wmu = (float*)(lds + 136192);   // w * sd2
  float* mvv = (float*)(lds + 136704);   // w * mu2
  float* vb  = (float*)(lds + 137216);   // [4]
  if (tid < 128) {
    float vE = sstE[tid * 4] + sstE[tid * 4 + 1] + sstE[tid * 4 + 2] + sstE[tid * 4 + 3];
    float vS = sstS[tid * 4] + sstS[tid * 4 + 1] + sstS[tid * 4 + 2] + sstS[tid * 4 + 3];
    float mE = vE, mS = vS;
    #pragma unroll
    for (int off = 1; off < 32; off <<= 1) {
      mE = fmaxf(mE, __shfl_xor(mE, off, 32));
      mS = fmaxf(mS, __shfl_xor(mS, off, 32));
    }
    float eE = __expf(vE - mE), eS = __expf(vS - mS);
    float sumE = eE, sumS = eS;
    #pragma unroll
    for (int off = 1; off < 32; off <<= 1) {
      sumE += __shfl_xor(sumE, off, 32);
      sumS += __shfl_xor(sumS, off, 32);
    }
    float awE = eE / sumE, awS = eS / sumS;
    size_t pidx = ((size_t)mb * 128 + tid) * 2;
    pair[pidx] = awE;
    pair[pidx + 1] = awS;
    float w = 0.5f * (awE + awS);
    float2 mi = ((float2*)minv)[tid];
    wmu[tid] = __fdividef(w, mi.y);
    mvv[tid] = w * mi.x;
  }
  __syncthreads();
  if (tid < 4) {
    float s = 0.f;
    #pragma unroll
    for (int i = 0; i < 32; i++) s += mvv[tid * 32 + i];
    vb[tid] = s;
  }
  __syncthreads();
  // ---- E10: pooled[b][c] = sum_{r in b} zhat[r][c]*wmu[r] + vb[b]
  {
    int c = tid;
    float ps[4] = {0.f, 0.f, 0.f, 0.f};
    #pragma unroll 8
    for (int r = 0; r < 128; r++) {
      float zv = (float)*(const bf16*)(lds + r * 1024 + ((c * 2) ^ ((r & 7) << 4)));
      ps[r >> 5] += zv * wmu[r];
    }
    #pragma unroll
    for (int b = 0; b < 4; b++)
      pooled[(size_t)(mb * 4 + b) * 512 + c] = ps[b] + vb[b];
  }
}

extern "C" void kernel_launch(void* const* d_in, const int* in_sizes, int n_in,
                              void* d_out, int out_size, void* d_ws, size_t ws_size,
                              hipStream_t stream) {
  const float* x     = (const float*)d_in[0];
  const float* pos   = (const float*)d_in[1];
  const float* w3    = (const float*)d_in[2];
  const float* bn3g  = (const float*)d_in[3];
  const float* bn3b  = (const float*)d_in[4];
  const float* bn3m  = (const float*)d_in[5];
  const float* bn3v  = (const float*)d_in[6];
  const float* w5    = (const float*)d_in[7];
  const float* bn5g  = (const float*)d_in[8];
  const float* bn5b  = (const float*)d_in[9];
  const float* bn5m  = (const float*)d_in[10];
  const float* bn5v  = (const float*)d_in[11];
  const float* wmix  = (const float*)d_in[12];
  const float* bnmg  = (const float*)d_in[13];
  const float* bnmb  = (const float*)d_in[14];
  const float* bnmm  = (const float*)d_in[15];
  const float* bnmv  = (const float*)d_in[16];
  const float* lng   = (const float*)d_in[17];
  const float* lnb   = (const float*)d_in[18];
  const float* edlng = (const float*)d_in[19];
  const float* edlnb = (const float*)d_in[20];
  const float* edw1  = (const float*)d_in[21];
  const float* edb1  = (const float*)d_in[22];
  const float* edw2  = (const float*)d_in[23];
  const float* eslng = (const float*)d_in[25];
  const float* eslnb = (const float*)d_in[26];
  const float* esw1  = (const float*)d_in[27];
  const float* esb1  = (const float*)d_in[28];
  const float* esw2  = (const float*)d_in[29];
  const float* ted   = (const float*)d_in[31];
  const float* tes   = (const float*)d_in[32];

  char* ws = (char*)d_ws;
  bf16* Acat  = (bf16*)ws;                        // 201,326,592 B
  bf16* wmixf = (bf16*)(ws + 201326592);          //   1,572,864 B
  bf16* w1f   = (bf16*)(ws + 202899456);          //     524,288 B
  float* b1f  = (float*)(ws + 203423744);         //       2,048 B

  float* feats  = (float*)d_out;
  float* pooled = feats + 33554432;   // B*T*C
  float* pair   = pooled + 1048576;   // + B*C

  fold_kernel<<<1024, 256, 0, stream>>>(wmix, bnmg, bnmv, edlng, edlnb, eslng, eslnb,
                                        edw1, esw1, edb1, esb1, wmixf, w1f, b1f);
  prep_kernel<<<NB, 512, 0, stream>>>(x, w3, bn3g, bn3b, bn3m, bn3v,
                                      w5, bn5g, bn5b, bn5m, bn5v, Acat);
  mega_kernel<<<MROWS / 128, 512, 0, stream>>>(
      Acat, wmixf, w1f, bnmg, bnmb, bnmm, bnmv, pos, lng, lnb,
      b1f, edw2, esw2, ted, tes, feats, pair, pooled);
}

// Round 15
// 370.896 us; speedup vs baseline: 1.0507x; 1.0507x over previous
//
#include <hip/hip_runtime.h>
#include <cstdint>

typedef __bf16 bf16;
typedef __attribute__((ext_vector_type(8))) __bf16 bf16x8;
typedef __attribute__((ext_vector_type(4))) float f32x4;

#define CEPS 1e-5f
#define MROWS 65536   // B*T
#define NB 2048       // B
#define CDIM 512
#define K3C 1536
#define MKT 24        // K3C / 64

// fast gelu: tanh form via native exp; |err| <= ~3e-3 absolute
__device__ __forceinline__ float gelu_f(float x) {
  float x2 = x * x;
  float u = x * (0.7978845608f + 0.0356774081f * x2);
  float e = __expf(2.0f * u);
  float th = 1.0f - __fdividef(2.0f, e + 1.0f);
  return 0.5f * x * (1.0f + th);
}

__device__ __forceinline__ void gload_lds16(const void* g, void* l) {
  using GP = const __attribute__((address_space(1))) void*;
  using LP = __attribute__((address_space(3))) void*;
  __builtin_amdgcn_global_load_lds(reinterpret_cast<GP>(reinterpret_cast<uintptr_t>(g)),
                                   reinterpret_cast<LP>(reinterpret_cast<uintptr_t>(l)),
                                   16, 0, 0);
}

__device__ __forceinline__ int xcd_swz(int bid, int nwg) {
  int q = nwg >> 3, r = nwg & 7;
  int xcd = bid & 7, i = bid >> 3;
  return (xcd < r ? xcd * (q + 1) : r * (q + 1) + (xcd - r) * q) + i;
}

// ---------------- fold kernel
__global__ __launch_bounds__(256) void fold_kernel(
    const float* __restrict__ wmix, const float* __restrict__ bnm_g, const float* __restrict__ bnm_v,
    const float* __restrict__ edg, const float* __restrict__ edb,
    const float* __restrict__ esg, const float* __restrict__ esb,
    const float* __restrict__ w1a, const float* __restrict__ w1b,
    const float* __restrict__ b1a, const float* __restrict__ b1b,
    bf16* __restrict__ wmixf, bf16* __restrict__ w1f, float* __restrict__ b1f) {
  __shared__ float red[4];
  int bid = blockIdx.x, tid = threadIdx.x;
  if (bid < 512) {
    int o = bid;
    float s = bnm_g[o] * rsqrtf(bnm_v[o] + CEPS);
    for (int c = tid; c < K3C; c += 256)
      wmixf[(size_t)o * K3C + c] = (bf16)(wmix[(size_t)o * K3C + c] * s);
  } else {
    int n = bid - 512;
    int half = (n < 256) ? 0 : 1;
    const float* g  = half ? esg : edg;
    const float* lb = half ? esb : edb;
    const float* w1 = half ? w1b : w1a;
    const float* b1 = half ? b1b : b1a;
    int nn = n & 255;
    float dot = 0.f;
    for (int c = tid; c < 512; c += 256) {
      float w = w1[(size_t)nn * 512 + c];
      w1f[(size_t)n * 512 + c] = (bf16)(w * g[c]);
      dot += w * lb[c];
    }
    #pragma unroll
    for (int off = 1; off < 64; off <<= 1) dot += __shfl_xor(dot, off, 64);
    if ((tid & 63) == 0) red[tid >> 6] = dot;
    __syncthreads();
    if (tid == 0) b1f[n] = b1[nn] + red[0] + red[1] + red[2] + red[3];
  }
}

// ---------------- prep (v1, proven)
__global__ __launch_bounds__(512) void prep_kernel(
    const float* __restrict__ x,
    const float* __restrict__ w3, const float* __restrict__ bn3g, const float* __restrict__ bn3b,
    const float* __restrict__ bn3m, const float* __restrict__ bn3v,
    const float* __restrict__ w5, const float* __restrict__ bn5g, const float* __restrict__ bn5b,
    const float* __restrict__ bn5m, const float* __restrict__ bn5v,
    bf16* __restrict__ Acat) {
  int b = blockIdx.x, c = threadIdx.x;
  const float4* xp = (const float4*)(x + ((size_t)b * 512 + c) * 64);
  float tf[32];
  #pragma unroll
  for (int i = 0; i < 16; i++) {
    float4 v = xp[i];
    tf[2 * i]     = 0.5f * (v.x + v.y);
    tf[2 * i + 1] = 0.5f * (v.z + v.w);
  }
  float s3 = bn3g[c] * rsqrtf(bn3v[c] + CEPS), t3 = bn3b[c] - bn3m[c] * s3;
  float s5 = bn5g[c] * rsqrtf(bn5v[c] + CEPS), t5 = bn5b[c] - bn5m[c] * s5;
  float w30 = w3[c * 3], w31 = w3[c * 3 + 1], w32 = w3[c * 3 + 2];
  float w50 = w5[c * 5], w51 = w5[c * 5 + 1], w52 = w5[c * 5 + 2], w53 = w5[c * 5 + 3], w54 = w5[c * 5 + 4];
  bf16* Ab = Acat + (size_t)b * 32 * K3C + c;
  #pragma unroll
  for (int t = 0; t < 32; t++) {
    float tm2 = (t >= 2) ? tf[t - 2] : 0.f;
    float tm1 = (t >= 1) ? tf[t - 1] : 0.f;
    float tp1 = (t < 31) ? tf[t + 1] : 0.f;
    float tp2 = (t < 30) ? tf[t + 2] : 0.f;
    float c3 = gelu_f((w30 * tm1 + w31 * tf[t] + w32 * tp1) * s3 + t3);
    float c5 = gelu_f((w50 * tm2 + w51 * tm1 + w52 * tf[t] + w53 * tp1 + w54 * tp2) * s5 + t5);
    Ab[t * K3C]        = (bf16)tf[t];
    Ab[t * K3C + 512]  = (bf16)c3;
    Ab[t * K3C + 1024] = (bf16)c5;
  }
}

// ---------------- mega kernel
#define MFMA1 __builtin_amdgcn_mfma_f32_16x16x32_bf16

#define PHASE(q)                                                              \
  {                                                                           \
    bf16x8 Bf[2][2];                                                          \
    _Pragma("unroll")                                                         \
    for (int i = 0; i < 2; i++) {                                             \
      Bf[i][0] = *(const bf16x8*)(lds + sl + bOff0 + (q) * 16384 + i * 2048); \
      Bf[i][1] = *(const bf16x8*)(lds + sl + bOff1 + (q) * 16384 + i * 2048); \
    }                                                                         \
    __builtin_amdgcn_s_barrier();                                             \
    __builtin_amdgcn_s_setprio(1);                                            \
    _Pragma("unroll")                                                         \
    for (int k2 = 0; k2 < 2; k2++)                                            \
      _Pragma("unroll")                                                       \
      for (int i = 0; i < 2; i++)                                             \
        _Pragma("unroll")                                                     \
        for (int mr = 0; mr < 4; mr++)                                        \
          acc[mr][2 * (q) + i] = MFMA1(Af[mr][k2], Bf[i][k2], acc[mr][2 * (q) + i], 0, 0, 0); \
    __builtin_amdgcn_s_setprio(0);                                            \
    if (stB) stageBq(sl, (q), t + 2);                                         \
  }

__global__ __launch_bounds__(512, 1) void mega_kernel(
    const bf16* __restrict__ Acat, const bf16* __restrict__ Bw, const bf16* __restrict__ w1f,
    const float* __restrict__ bn_g, const float* __restrict__ bn_b,
    const float* __restrict__ bn_m, const float* __restrict__ bn_v,
    const float* __restrict__ pos, const float* __restrict__ lng, const float* __restrict__ lnb,
    const float* __restrict__ b1f, const float* __restrict__ w2a, const float* __restrict__ w2b,
    const float* __restrict__ ta, const float* __restrict__ tb,
    float* __restrict__ feats, float* __restrict__ pair, float* __restrict__ pooled) {
  __shared__ char lds[163840];
  int tid = threadIdx.x;
  int wv = tid >> 6, lane = tid & 63;
  int wm = wv >> 2, wn = wv & 3;
  int fr = lane & 15, kq = lane >> 4;
  int mb = xcd_swz(blockIdx.x, gridDim.x);   // 512 m-blocks

  const size_t AKB = 3072;
  const char* Ablk = (const char*)Acat + (size_t)mb * 128 * AKB;

  int r8 = tid >> 3;
  int colx = ((tid & 7) << 4) ^ ((r8 & 7) << 4);
  const char* pA = Ablk + (size_t)r8 * AKB + colx;
  int r32 = r8 & 31, st0 = r8 >> 5;
  const char* pB = (const char*)Bw + (size_t)(st0 * 128 + r32) * AKB
                 + (((tid & 7) << 4) ^ ((r32 & 7) << 4));
  const int dstIdx = tid * 16;

  int e0 = (kq << 4) ^ ((fr & 7) << 4);
  int e1 = (64 | (kq << 4)) ^ ((fr & 7) << 4);
  int aB_ = (wm * 64 + fr) * 128;
  int bB_ = 16384 + (wn * 32 + fr) * 128;
  const int aOff0 = aB_ + e0, aOff1 = aB_ + e1;
  const int bOff0 = bB_ + e0, bOff1 = bB_ + e1;

  auto stageA = [&](int slot, int t) {
    char* d = lds + slot + dstIdx;
    const char* s = pA + (size_t)t * 128;
    gload_lds16(s, d);
    gload_lds16(s + 64 * AKB, d + 8192);
  };
  auto stageBq = [&](int slot, int q, int t) {
    char* d = lds + slot + 16384 + q * 16384 + dstIdx;
    const char* s = pB + (size_t)q * 32 * AKB + (size_t)t * 128;
    gload_lds16(s, d);
    gload_lds16(s + 256 * AKB, d + 8192);
  };

  const f32x4 fz = {0.f, 0.f, 0.f, 0.f};
  f32x4 acc[4][8];
  #pragma unroll
  for (int i = 0; i < 4; i++)
    #pragma unroll
    for (int j = 0; j < 8; j++) acc[i][j] = fz;

  stageA(0, 0);
  #pragma unroll
  for (int q = 0; q < 4; q++) stageBq(0, q, 0);
  #pragma unroll
  for (int q = 0; q < 4; q++) stageBq(81920, q, 1);
  asm volatile("s_waitcnt vmcnt(8)" ::: "memory");
  __builtin_amdgcn_s_barrier();

  for (int t = 0; t < MKT; t++) {
    const int sl = (t & 1) * 81920;
    const bool stA = (t + 1 < MKT), stB = (t + 2 < MKT);
    if (stA) stageA(sl ^ 81920, t + 1);
    bf16x8 Af[4][2];
    #pragma unroll
    for (int mr = 0; mr < 4; mr++) {
      Af[mr][0] = *(const bf16x8*)(lds + sl + aOff0 + mr * 2048);
      Af[mr][1] = *(const bf16x8*)(lds + sl + aOff1 + mr * 2048);
    }
    PHASE(0);
    __builtin_amdgcn_s_barrier();
    PHASE(1);
    __builtin_amdgcn_s_barrier();
    PHASE(2);
    __builtin_amdgcn_s_barrier();
    PHASE(3);
    if (t < MKT - 2) {
      asm volatile("s_waitcnt vmcnt(8)" ::: "memory");
    } else if (t == MKT - 2) {
      asm volatile("s_waitcnt vmcnt(0)" ::: "memory");
    }
    __builtin_amdgcn_s_barrier();
  }

  // ---- E1: ctx = gelu(acc + bn_bias) in-register
  {
    float biasm[8];
    #pragma unroll
    for (int nr = 0; nr < 8; nr++) {
      int n = wn * 128 + nr * 16 + fr;
      float s = bn_g[n] * rsqrtf(bn_v[n] + CEPS);
      biasm[nr] = bn_b[n] - bn_m[n] * s;
    }
    #pragma unroll
    for (int mr = 0; mr < 4; mr++)
      #pragma unroll
      for (int nr = 0; nr < 8; nr++)
        #pragma unroll
        for (int j = 0; j < 4; j++)
          acc[mr][nr][j] = gelu_f(acc[mr][nr][j] + biasm[nr]);
  }
  __syncthreads();
  // ---- E2: stage tf tile [128 rows][1024B] swizzled into lds[0..131072)
  {
    const char* ptf = Ablk + (size_t)wv * AKB + ((lane * 16) ^ (wv << 4));
    char* d = lds + wv * 1024 + lane * 16;
    #pragma unroll
    for (int l = 0; l < 16; l++) gload_lds16(ptf + (size_t)l * 8 * AKB, d + l * 8192);
  }
  __syncthreads();
  float* sst  = (float*)(lds + 131072);   // [128][4] float2
  float* minv = (float*)(lds + 135168);   // [128] float2 (mu, inv)
  // ---- E3: z = ctx + tf + pos; stats1
  {
    float s1[4][4], s2[4][4];
    #pragma unroll
    for (int mr = 0; mr < 4; mr++)
      #pragma unroll
      for (int j = 0; j < 4; j++) { s1[mr][j] = 0.f; s2[mr][j] = 0.f; }
    #pragma unroll
    for (int mr = 0; mr < 4; mr++)
      #pragma unroll
      for (int j = 0; j < 4; j++) {
        int r = wm * 64 + mr * 16 + kq * 4 + j;
        int swz = (r & 7) << 4;
        #pragma unroll
        for (int nr = 0; nr < 8; nr++) {
          int c = wn * 128 + nr * 16 + fr;
          float tfv = (float)*(const bf16*)(lds + r * 1024 + ((c * 2) ^ swz));
          float z = acc[mr][nr][j] + tfv + pos[(r & 31) * 512 + c];
          acc[mr][nr][j] = z;
          s1[mr][j] += z; s2[mr][j] += z * z;
        }
      }
    #pragma unroll
    for (int mr = 0; mr < 4; mr++)
      #pragma unroll
      for (int j = 0; j < 4; j++)
        #pragma unroll
        for (int off = 1; off < 16; off <<= 1) {
          s1[mr][j] += __shfl_xor(s1[mr][j], off, 64);
          s2[mr][j] += __shfl_xor(s2[mr][j], off, 64);
        }
    if (fr == 0) {
      #pragma unroll
      for (int mr = 0; mr < 4; mr++)
        #pragma unroll
        for (int j = 0; j < 4; j++) {
          int r = wm * 64 + mr * 16 + kq * 4 + j;
          ((float2*)sst)[r * 4 + wn] = make_float2(s1[mr][j], s2[mr][j]);
        }
    }
  }
  __syncthreads();
  if (tid < 128) {
    float a = 0.f, b = 0.f;
    #pragma unroll
    for (int w = 0; w < 4; w++) { float2 v = ((float2*)sst)[tid * 4 + w]; a += v.x; b += v.y; }
    float mu = a * (1.f / 512.f);
    float var = b * (1.f / 512.f) - mu * mu;
    ((float2*)minv)[tid] = make_float2(mu, rsqrtf(var + CEPS));
  }
  __syncthreads();
  // ---- E5: feats = (z-mu)*inv*g + b; stats2
  {
    float g_[8], b_[8];
    #pragma unroll
    for (int nr = 0; nr < 8; nr++) {
      int c = wn * 128 + nr * 16 + fr;
      g_[nr] = lng[c]; b_[nr] = lnb[c];
    }
    float t1[4][4], t2[4][4];
    #pragma unroll
    for (int mr = 0; mr < 4; mr++)
      #pragma unroll
      for (int j = 0; j < 4; j++) { t1[mr][j] = 0.f; t2[mr][j] = 0.f; }
    #pragma unroll
    for (int mr = 0; mr < 4; mr++)
      #pragma unroll
      for (int j = 0; j < 4; j++) {
        int r = wm * 64 + mr * 16 + kq * 4 + j;
        float2 mi = ((float2*)minv)[r];
        #pragma unroll
        for (int nr = 0; nr < 8; nr++) {
          int c = wn * 128 + nr * 16 + fr;
          float f = (acc[mr][nr][j] - mi.x) * mi.y * g_[nr] + b_[nr];
          acc[mr][nr][j] = f;
          feats[((size_t)mb * 128 + r) * 512 + c] = f;
          t1[mr][j] += f; t2[mr][j] += f * f;
        }
      }
    #pragma unroll
    for (int mr = 0; mr < 4; mr++)
      #pragma unroll
      for (int j = 0; j < 4; j++)
        #pragma unroll
        for (int off = 1; off < 16; off <<= 1) {
          t1[mr][j] += __shfl_xor(t1[mr][j], off, 64);
          t2[mr][j] += __shfl_xor(t2[mr][j], off, 64);
        }
    __syncthreads();
    if (fr == 0) {
      #pragma unroll
      for (int mr = 0; mr < 4; mr++)
        #pragma unroll
        for (int j = 0; j < 4; j++) {
          int r = wm * 64 + mr * 16 + kq * 4 + j;
          ((float2*)sst)[r * 4 + wn] = make_float2(t1[mr][j], t2[mr][j]);
        }
    }
  }
  __syncthreads();
  if (tid < 128) {
    float a = 0.f, b = 0.f;
    #pragma unroll
    for (int w = 0; w < 4; w++) { float2 v = ((float2*)sst)[tid * 4 + w]; a += v.x; b += v.y; }
    float mu = a * (1.f / 512.f);
    float var = b * (1.f / 512.f) - mu * mu;
    ((float2*)minv)[tid] = make_float2(mu, rsqrtf(var + CEPS));
  }
  __syncthreads();
  // ---- E6: zhat -> LDS [0..131072), swizzled; alive through pooled
  #pragma unroll
  for (int mr = 0; mr < 4; mr++)
    #pragma unroll
    for (int j = 0; j < 4; j++) {
      int r = wm * 64 + mr * 16 + kq * 4 + j;
      int swz = (r & 7) << 4;
      float2 mi = ((float2*)minv)[r];
      #pragma unroll
      for (int nr = 0; nr < 8; nr++) {
        int c = wn * 128 + nr * 16 + fr;
        *(bf16*)(lds + r * 1024 + ((c * 2) ^ swz)) = (bf16)((acc[mr][nr][j] - mi.x) * mi.y);
      }
    }
  __syncthreads();
  // ---- snapshot (mu2, inv2) before E7's DMA clobbers the minv region
  float2 miKeep = make_float2(0.f, 1.f);
  if (tid < 128) miKeep = ((float2*)minv)[tid];
  __syncthreads();
  // ---- E7: attn via LDS-staged w1f column-slices; acc -> h [4 mr][h*4+nr]
  #pragma unroll
  for (int i = 0; i < 4; i++)
    #pragma unroll
    for (int j = 0; j < 8; j++) acc[i][j] = fz;
  float b1l[8], w2l[8];
  #pragma unroll
  for (int h = 0; h < 2; h++) {
    float tv = fminf(fmaxf(h ? tb[0] : ta[0], 0.25f), 4.0f);
    #pragma unroll
    for (int nr = 0; nr < 4; nr++) {
      int np = wn * 64 + nr * 16 + fr;
      b1l[h * 4 + nr] = b1f[h * 256 + np];
      w2l[h * 4 + nr] = (h ? w2b[np] : w2a[np]) / tv;
    }
  }
  {
    const char* pW = (const char*)w1f + (size_t)r8 * 1024 + colx;
    int azB = (wm * 64 + fr) * 1024;
    int abB = 131072 + (wn * 64 + fr) * 128;
    const int azOff0 = azB + e0, azOff1 = azB + e1;
    const int abOff0 = abB + e0, abOff1 = abB + e1;
    #pragma unroll
    for (int h = 0; h < 2; h++) {
      {
        char* d = lds + 131072 + dstIdx;
        #pragma unroll
        for (int l = 0; l < 4; l++)
          gload_lds16(pW + h * 262144 + l * 65536, d + l * 8192);
      }
      __syncthreads();
      for (int kk = 0; kk < 8; kk++) {
        bf16x8 pf[4];
        if (kk < 7) {
          #pragma unroll
          for (int l = 0; l < 4; l++)
            pf[l] = *(const bf16x8*)(pW + h * 262144 + l * 65536 + (kk + 1) * 128);
        }
        bf16x8 Az[4][2], Bz[4][2];
        #pragma unroll
        for (int mr = 0; mr < 4; mr++) {
          Az[mr][0] = *(const bf16x8*)(lds + azOff0 + mr * 16384 + kk * 128);
          Az[mr][1] = *(const bf16x8*)(lds + azOff1 + mr * 16384 + kk * 128);
        }
        #pragma unroll
        for (int nr = 0; nr < 4; nr++) {
          Bz[nr][0] = *(const bf16x8*)(lds + abOff0 + nr * 2048);
          Bz[nr][1] = *(const bf16x8*)(lds + abOff1 + nr * 2048);
        }
        __builtin_amdgcn_s_setprio(1);
        #pragma unroll
        for (int k2 = 0; k2 < 2; k2++)
          #pragma unroll
          for (int mr = 0; mr < 4; mr++)
            #pragma unroll
            for (int nr = 0; nr < 4; nr++)
              acc[mr][h * 4 + nr] = MFMA1(Az[mr][k2], Bz[nr][k2], acc[mr][h * 4 + nr], 0, 0, 0);
        __builtin_amdgcn_s_setprio(0);
        if (kk < 7) {
          __syncthreads();
          char* d = lds + 131072 + dstIdx;
          #pragma unroll
          for (int l = 0; l < 4; l++) *(bf16x8*)(d + l * 8192) = pf[l];
          __syncthreads();
        }
      }
      __syncthreads();
    }
  }
  // ---- E8: path partials: sstE/sstS[r][wn]
  float* sstE = (float*)(lds + 131072);  // [128][4]
  float* sstS = (float*)(lds + 133120);
  {
    float pE[4][4], pS[4][4];
    #pragma unroll
    for (int mr = 0; mr < 4; mr++)
      #pragma unroll
      for (int j = 0; j < 4; j++) { pE[mr][j] = 0.f; pS[mr][j] = 0.f; }
    #pragma unroll
    for (int mr = 0; mr < 4; mr++)
      #pragma unroll
      for (int j = 0; j < 4; j++)
        #pragma unroll
        for (int q8 = 0; q8 < 8; q8++) {
          float hh = gelu_f(acc[mr][q8][j] + b1l[q8]) * w2l[q8];
          if (q8 < 4) pE[mr][j] += hh; else pS[mr][j] += hh;
        }
    #pragma unroll
    for (int mr = 0; mr < 4; mr++)
      #pragma unroll
      for (int j = 0; j < 4; j++)
        #pragma unroll
        for (int off = 1; off < 16; off <<= 1) {
          pE[mr][j] += __shfl_xor(pE[mr][j], off, 64);
          pS[mr][j] += __shfl_xor(pS[mr][j], off, 64);
        }
    if (fr == 0) {
      #pragma unroll
      for (int mr = 0; mr < 4; mr++)
        #pragma unroll
        for (int j = 0; j < 4; j++) {
          int r = wm * 64 + mr * 16 + kq * 4 + j;
          sstE[r * 4 + wn] = pE[mr][j];
          sstS[r * 4 + wn] = pS[mr][j];
        }
    }
  }
  __syncthreads();
  // ---- E9: softmax over T per batch; pair; pooled weights
  float* wmu = (float*)(lds + 136192);   // w * sd2
  float* mvv = (float*)(lds + 136704);   // w * mu2
  float* vb  = (float*)(lds + 137216);   // [4]
  if (tid < 128) {
    float vE = sstE[tid * 4] + sstE[tid * 4 + 1] + sstE[tid * 4 + 2] + sstE[tid * 4 + 3];
    float vS = sstS[tid * 4] + sstS[tid * 4 + 1] + sstS[tid * 4 + 2] + sstS[tid * 4 + 3];
    float mE = vE, mS = vS;
    #pragma unroll
    for (int off = 1; off < 32; off <<= 1) {
      mE = fmaxf(mE, __shfl_xor(mE, off, 32));
      mS = fmaxf(mS, __shfl_xor(mS, off, 32));
    }
    float eE = __expf(vE - mE), eS = __expf(vS - mS);
    float sumE = eE, sumS = eS;
    #pragma unroll
    for (int off = 1; off < 32; off <<= 1) {
      sumE += __shfl_xor(sumE, off, 32);
      sumS += __shfl_xor(sumS, off, 32);
    }
    float awE = eE / sumE, awS = eS / sumS;
    size_t pidx = ((size_t)mb * 128 + tid) * 2;
    pair[pidx] = awE;
    pair[pidx + 1] = awS;
    float w = 0.5f * (awE + awS);
    wmu[tid] = __fdividef(w, miKeep.y);
    mvv[tid] = w * miKeep.x;
  }
  __syncthreads();
  if (tid < 4) {
    float s = 0.f;
    #pragma unroll
    for (int i = 0; i < 32; i++) s += mvv[tid * 32 + i];
    vb[tid] = s;
  }
  __syncthreads();
  // ---- E10: pooled[b][c] = sum_{r in b} zhat[r][c]*wmu[r] + vb[b]
  {
    int c = tid;
    float ps[4] = {0.f, 0.f, 0.f, 0.f};
    #pragma unroll 8
    for (int r = 0; r < 128; r++) {
      float zv = (float)*(const bf16*)(lds + r * 1024 + ((c * 2) ^ ((r & 7) << 4)));
      ps[r >> 5] += zv * wmu[r];
    }
    #pragma unroll
    for (int b = 0; b < 4; b++)
      pooled[(size_t)(mb * 4 + b) * 512 + c] = ps[b] + vb[b];
  }
}

extern "C" void kernel_launch(void* const* d_in, const int* in_sizes, int n_in,
                              void* d_out, int out_size, void* d_ws, size_t ws_size,
                              hipStream_t stream) {
  const float* x     = (const float*)d_in[0];
  const float* pos   = (const float*)d_in[1];
  const float* w3    = (const float*)d_in[2];
  const float* bn3g  = (const float*)d_in[3];
  const float* bn3b  = (const float*)d_in[4];
  const float* bn3m  = (const float*)d_in[5];
  const float* bn3v  = (const float*)d_in[6];
  const float* w5    = (const float*)d_in[7];
  const float* bn5g  = (const float*)d_in[8];
  const float* bn5b  = (const float*)d_in[9];
  const float* bn5m  = (const float*)d_in[10];
  const float* bn5v  = (const float*)d_in[11];
  const float* wmix  = (const float*)d_in[12];
  const float* bnmg  = (const float*)d_in[13];
  const float* bnmb  = (const float*)d_in[14];
  const float* bnmm  = (const float*)d_in[15];
  const float* bnmv  = (const float*)d_in[16];
  const float* lng   = (const float*)d_in[17];
  const float* lnb   = (const float*)d_in[18];
  const float* edlng = (const float*)d_in[19];
  const float* edlnb = (const float*)d_in[20];
  const float* edw1  = (const float*)d_in[21];
  const float* edb1  = (const float*)d_in[22];
  const float* edw2  = (const float*)d_in[23];
  const float* eslng = (const float*)d_in[25];
  const float* eslnb = (const float*)d_in[26];
  const float* esw1  = (const float*)d_in[27];
  const float* esb1  = (const float*)d_in[28];
  const float* esw2  = (const float*)d_in[29];
  const float* ted   = (const float*)d_in[31];
  const float* tes   = (const float*)d_in[32];

  char* ws = (char*)d_ws;
  bf16* Acat  = (bf16*)ws;                        // 201,326,592 B
  bf16* wmixf = (bf16*)(ws + 201326592);          //   1,572,864 B
  bf16* w1f   = (bf16*)(ws + 202899456);          //     524,288 B
  float* b1f  = (float*)(ws + 203423744);         //       2,048 B

  float* feats  = (float*)d_out;
  float* pooled = feats + 33554432;   // B*T*C
  float* pair   = pooled + 1048576;   // + B*C

  fold_kernel<<<1024, 256, 0, stream>>>(wmix, bnmg, bnmv, edlng, edlnb, eslng, eslnb,
                                        edw1, esw1, edb1, esb1, wmixf, w1f, b1f);
  prep_kernel<<<NB, 512, 0, stream>>>(x, w3, bn3g, bn3b, bn3m, bn3v,
                                      w5, bn5g, bn5b, bn5m, bn5v, Acat);
  mega_kernel<<<MROWS / 128, 512, 0, stream>>>(
      Acat, wmixf, w1f, bnmg, bnmb, bnmm, bnmv, pos, lng, lnb,
      b1f, edw2, esw2, ted, tes, feats, pair, pooled);
}